// Round 15
// baseline (295.659 us; speedup 1.0000x reference)
//
#include <hip/hip_runtime.h>

#define NN 50000
#define NE 400000

typedef unsigned short u16;
typedef unsigned int   u32;
typedef __bf16 bf16x4 __attribute__((ext_vector_type(4)));
typedef __bf16 bf16x8 __attribute__((ext_vector_type(8)));
typedef float  f32x16 __attribute__((ext_vector_type(16)));

union ABFrag { bf16x8 v; bf16x4 h[2]; };
union BFrag  { uint4 u; bf16x8 v; };

__device__ __forceinline__ u16 f2bfu(float f) {
  u32 u = __builtin_bit_cast(u32, f);
  return (u16)((u + 0x7FFFu + ((u >> 16) & 1u)) >> 16);  // RNE f32->bf16
}
__device__ __forceinline__ float bf2f(u16 u) {
  return __builtin_bit_cast(float, (u32)u << 16);
}

// ---------------- prep: cvt + weight-pack + hist in ONE launch ---------------
// Pack for mfma_f32_32x32x16_bf16 B-operand:
// P[((t16*256+n)*2+h)*8+j] = W[16*t16 + 4h + (j&3) + 8*(j>>2)][n]
__device__ __forceinline__ void pack_one(const float* __restrict__ W,
                                         u16* __restrict__ P, int idx) {
  int k = idx >> 8, n = idx & 255;
  int t16 = k >> 4, kp = k & 15;
  int hh = (kp >> 2) & 1;
  int j = (kp & 3) | (((kp >> 3) & 1) << 2);
  P[(((t16 << 8) + n) << 4) + (hh << 3) + j] = f2bfu(W[idx]);
}

#define NB_CVT  12500
#define NB_PACK 1088
#define NB_HIST 1563

__global__ __launch_bounds__(256) void k_prep(
    const float* __restrict__ nodes, u16* __restrict__ nodes_bf,
    const float* __restrict__ Wm, const float* __restrict__ W0,
    const float* __restrict__ W1, const float* __restrict__ W2,
    u16* __restrict__ Pm, u16* __restrict__ P0,
    u16* __restrict__ P1, u16* __restrict__ P2,
    const int* __restrict__ recv, int* __restrict__ cnt)
{
  int b = blockIdx.x, t = threadIdx.x;
  if (b < NB_CVT) {
    int i = b * 256 + t;
    float4 f = ((const float4*)nodes)[i];
    ushort4 o;
    o.x = f2bfu(f.x); o.y = f2bfu(f.y); o.z = f2bfu(f.z); o.w = f2bfu(f.w);
    ((ushort4*)nodes_bf)[i] = o;
  } else if (b < NB_CVT + NB_PACK) {
    int idx = (b - NB_CVT) * 256 + t;
    const int S0 = 320 * 256, S1 = S0 + 65536, S2 = S1 + 65536;
    if (idx < S0)      pack_one(Wm, Pm, idx);
    else if (idx < S1) pack_one(W0, P0, idx - S0);
    else if (idx < S2) pack_one(W1, P1, idx - S1);
    else               pack_one(W2, P2, idx - S2);
  } else {
    int i = (b - NB_CVT - NB_PACK) * 256 + t;
    if (i < NE) atomicAdd(&cnt[recv[i]], 1);
  }
}

// ---------------- counting-sort scan + scatter -------------------------------
__global__ __launch_bounds__(256) void k_scan1(const int* __restrict__ cnt,
                                               int* __restrict__ loc,
                                               int* __restrict__ bsum) {
  __shared__ int sm[256];
  int t = threadIdx.x, i = blockIdx.x * 256 + t;
  int v = (i < NN) ? cnt[i] : 0;
  sm[t] = v;
  __syncthreads();
  #pragma unroll
  for (int d = 1; d < 256; d <<= 1) {
    int x = sm[t];
    int y = (t >= d) ? sm[t - d] : 0;
    __syncthreads();
    sm[t] = x + y;
    __syncthreads();
  }
  if (i < NN) loc[i] = sm[t] - v;
  if (t == 255) bsum[blockIdx.x] = sm[255];
}

__global__ __launch_bounds__(256) void k_scan2(int* __restrict__ bsum,
                                               int* __restrict__ bpre, int nb) {
  __shared__ int sm[256];
  int t = threadIdx.x;
  int v = (t < nb) ? bsum[t] : 0;
  sm[t] = v;
  __syncthreads();
  #pragma unroll
  for (int d = 1; d < 256; d <<= 1) {
    int x = sm[t];
    int y = (t >= d) ? sm[t - d] : 0;
    __syncthreads();
    sm[t] = x + y;
    __syncthreads();
  }
  if (t < nb) bpre[t] = sm[t] - v;
}

__global__ __launch_bounds__(256) void k_scan3(const int* __restrict__ loc,
                                               const int* __restrict__ bpre,
                                               int* __restrict__ offs,
                                               int* __restrict__ cursor) {
  int i = blockIdx.x * 256 + threadIdx.x;
  if (i < NN) {
    int o = loc[i] + bpre[blockIdx.x];
    offs[i] = o;
    cursor[i] = o;
  }
  if (i == NN - 1) offs[NN] = NE;
}

__global__ __launch_bounds__(256) void k_scatter(
    const int* __restrict__ snd, const int* __restrict__ recv,
    int* __restrict__ cursor, int2* __restrict__ s_pair) {
  int e = blockIdx.x * 256 + threadIdx.x;
  if (e < NE) {
    int p = atomicAdd(&cursor[recv[e]], 1);
    int2 pr; pr.x = snd[e]; pr.y = e;
    s_pair[p] = pr;
  }
}

// ---------------- aggregation: half-wave paired volleys (R13, at floor) ------
__global__ __launch_bounds__(256) void k_aggr(
    const u16* __restrict__ nodes_bf, const float* __restrict__ edges,
    const int* __restrict__ offs, const int2* __restrict__ s_pair,
    u16* __restrict__ X)
{
  const int node = blockIdx.x * 4 + (threadIdx.x >> 6);
  const int lane = threadIdx.x & 63;
  const int h = lane >> 5, c = lane & 31;
  const int beg = offs[node], end = offs[node + 1];

  float a0 = 0.f, a1 = 0.f, a2 = 0.f, a3 = 0.f;
  float a4 = 0.f, a5 = 0.f, a6 = 0.f, a7 = 0.f;
  float ae0 = 0.f, ae1 = 0.f;

  for (int jb = beg; jb < end; jb += 8) {
    int j = jb + (lane & 7);
    if (j >= end) j = end - 1;
    int2 pr = s_pair[j];
    const int rem = end - jb;

#define PGATHER(K) \
    int s##K = __shfl(pr.x, 2 * K + h); \
    int e##K = __shfl(pr.y, 2 * K + h); \
    uint4 n##K = *(const uint4*)(nodes_bf + (size_t)s##K * 256 + (c << 3)); \
    float2 v##K = *(const float2*)(edges + (size_t)e##K * 64 + (c << 1));

    PGATHER(0) PGATHER(1) PGATHER(2) PGATHER(3)
#undef PGATHER

#define PACC(K) \
    if (rem > 2 * K + h) { \
      a0 += bf2f((u16)n##K.x); a1 += bf2f((u16)(n##K.x >> 16)); \
      a2 += bf2f((u16)n##K.y); a3 += bf2f((u16)(n##K.y >> 16)); \
      a4 += bf2f((u16)n##K.z); a5 += bf2f((u16)(n##K.z >> 16)); \
      a6 += bf2f((u16)n##K.w); a7 += bf2f((u16)(n##K.w >> 16)); \
      ae0 += v##K.x; ae1 += v##K.y; }

    PACC(0) PACC(1) PACC(2) PACC(3)
#undef PACC
  }

  a0 += __shfl_xor(a0, 32); a1 += __shfl_xor(a1, 32);
  a2 += __shfl_xor(a2, 32); a3 += __shfl_xor(a3, 32);
  a4 += __shfl_xor(a4, 32); a5 += __shfl_xor(a5, 32);
  a6 += __shfl_xor(a6, 32); a7 += __shfl_xor(a7, 32);
  ae0 += __shfl_xor(ae0, 32); ae1 += __shfl_xor(ae1, 32);

  if (lane < 32) {
    u16* xr = X + (size_t)node * 320;
    uint4 o;
    o.x = (u32)f2bfu(a0) | ((u32)f2bfu(a1) << 16);
    o.y = (u32)f2bfu(a2) | ((u32)f2bfu(a3) << 16);
    o.z = (u32)f2bfu(a4) | ((u32)f2bfu(a5) << 16);
    o.w = (u32)f2bfu(a6) | ((u32)f2bfu(a7) << 16);
    *(uint4*)(xr + (c << 3)) = o;
    *(u32*)(xr + 256 + (c << 1)) =
        (u32)f2bfu(ae0) | ((u32)f2bfu(ae1) << 16);
  }
}

// ---------------- fused dense chain: 32x32x16 MFMA, 16 waves x 32x32 tile ----
// 1024 threads = 16 waves: wr = w>>3 (32-row half), wc = w&7 (32-col block).
// acc = f32x16 (16 VGPRs) -> live set < 64-reg tier (spill-free, R8-proven).
// LDS ~62 KB -> 2 blocks/CU = 32 waves/CU (R13's TLP restored).
// Bt staging: per-wave contiguous 1KB LDS writes (conflict-free); global src
// is 32B-strided but L1/L2-hot. C/D layout verified in R14 (absmax unchanged).

#define AT_ADDR(r, c) (atb + ((((r) * 640) + ((c) * 2)) ^ (((r) & 7) << 4)))

#define MFMA_STEP32(t) \
  _Pragma("unroll") \
  for (int s = 0; s < 2; ++s) { \
    ABFrag a; \
    const int kc = ((t) << 5) + (s << 4) + (hA << 2); \
    a.h[0] = *(const bf16x4*)AT_ADDR(mrow, kc); \
    a.h[1] = *(const bf16x4*)AT_ADDR(mrow, kc + 8); \
    BFrag b; \
    b.u = *(const uint4*)&Bt[(s << 12) + (hA << 11) + (ncol << 3)]; \
    acc = __builtin_amdgcn_mfma_f32_32x32x16_bf16(a.v, b.v, acc, 0, 0, 0); \
  }

#define RUN_LAYER32(wp, T) do { \
  const u16* pb = (wp) + (sB << 12) + (nB << 4) + (hB << 3); \
  uint4 p0 = *(const uint4*)pb; \
  _Pragma("unroll 1") \
  for (int t = 0; t < (T); ++t) { \
    __syncthreads(); \
    *(uint4*)&Bt[btidx] = p0; \
    if (t + 1 < (T)) p0 = *(const uint4*)(pb + ((size_t)(t + 1) << 13)); \
    __syncthreads(); \
    MFMA_STEP32(t) \
  } \
} while (0)

// rows held by this lane: row(rg) = (rg&3) + 8*(rg>>2) + 4*hA (in 32-row half)
#define ROW_OF(rg) (((rg) & 3) + (((rg) >> 2) << 3) + (hA << 2))

#define LN_STATS32() do { \
  _Pragma("unroll") \
  for (int rg = 0; rg < 16; ++rg) { \
    float v = acc[rg]; \
    float s = v, s2 = v * v; \
    s  += __shfl_xor(s, 1);  s  += __shfl_xor(s, 2);  s  += __shfl_xor(s, 4); \
    s  += __shfl_xor(s, 8);  s  += __shfl_xor(s, 16); \
    s2 += __shfl_xor(s2, 1); s2 += __shfl_xor(s2, 2); s2 += __shfl_xor(s2, 4); \
    s2 += __shfl_xor(s2, 8); s2 += __shfl_xor(s2, 16); \
    if (m32 == 0) { int mm = wr32 + ROW_OF(rg); red[mm][wcH] = s; red[mm][wcH + 1] = s2; } \
  } \
  __syncthreads(); \
  if (tid < 64) { \
    float s = 0.f, s2 = 0.f; \
    _Pragma("unroll") \
    for (int i = 0; i < 8; ++i) { s += red[tid][2 * i]; s2 += red[tid][2 * i + 1]; } \
    float mu  = s * (1.f / 256.f); \
    float var = s2 * (1.f / 256.f) - mu * mu; \
    murs[tid][0] = mu; murs[tid][1] = rsqrtf(var + 1e-6f); \
  } \
  __syncthreads(); \
} while (0)

__global__ __launch_bounds__(1024)
void k_fused(
    const u16* __restrict__ X, const float* __restrict__ nodes,
    const u16* __restrict__ wm, const u16* __restrict__ w0,
    const u16* __restrict__ w1, const u16* __restrict__ w2,
    const float* __restrict__ b0, const float* __restrict__ b1,
    const float* __restrict__ b2,
    const float* __restrict__ lnAs, const float* __restrict__ lnAb,
    const float* __restrict__ lnOs, const float* __restrict__ lnOb,
    float* __restrict__ out)
{
  __shared__ u16 At[64 * 320];     // XOR-swizzled: byte ^= (row&7)<<4
  __shared__ u16 Bt[8192];         // K=32 step: [s][h][n][8]
  __shared__ float red[64][16];
  __shared__ float murs[64][2];

  const int tid = threadIdx.x;
  const int lane = tid & 63;
  const int w = tid >> 6;                // 0..15
  const int wr32 = (w >> 3) << 5;        // row base (0 or 32)
  const int wc = w & 7;                  // col-block (32 cols each)
  const int wcH = wc << 1;
  const int m32 = lane & 31, hA = lane >> 5;
  const int ncol = (wc << 5) + m32;      // this lane's output column
  const int mrow = wr32 + m32;
  const int r0 = blockIdx.x * 64;
  // Bt staging assignment: contiguous LDS writes per wave
  const int sB = tid >> 9, hB = (tid >> 8) & 1, nB = tid & 255;
  const int btidx = (sB << 12) + (hB << 11) + (nB << 3);

  char* const atb = (char*)At;

  // ---- stage X (bf16, K=320) into swizzled At ----
  #pragma unroll
  for (int it = 0; it < 3; ++it) {
    int c = tid + it * 1024;             // 2560 chunks of 16B
    if (c < 2560) {
      int r = c / 40, seg = c - r * 40;
      int row = r0 + r;
      uint4 v = {0u, 0u, 0u, 0u};
      if (row < NN) v = *(const uint4*)(X + (size_t)row * 320 + seg * 8);
      *(uint4*)(atb + ((r * 640 + seg * 16) ^ ((r & 7) << 4))) = v;
    }
  }

  f32x16 acc;
  #pragma unroll
  for (int i = 0; i < 16; ++i) acc[i] = 0.f;

  // ---- GEMM: X @ Wmsg (K=320, 10 steps of 32) ----
  RUN_LAYER32(wm, 10);

  // ---- aggr epilogue: v = relu(acc) + nodes ----
  #pragma unroll
  for (int rg = 0; rg < 16; ++rg) {
    int row = r0 + wr32 + ROW_OF(rg);
    float nv = (row < NN) ? nodes[(size_t)row * 256 + ncol] : 0.f;
    acc[rg] = fmaxf(acc[rg], 0.f) + nv;
  }
  LN_STATS32();                          // barrier inside also fences At reads
  // h = LN_a(v) -> bf16 into At (residual + next A operand)
  {
    float scl = lnAs[ncol], bia = lnAb[ncol];
    #pragma unroll
    for (int rg = 0; rg < 16; ++rg) {
      int mm = wr32 + ROW_OF(rg);
      float hv = (acc[rg] - murs[mm][0]) * murs[mm][1] * scl + bia;
      *(u16*)AT_ADDR(mm, ncol) = f2bfu(hv);
      acc[rg] = 0.f;
    }
  }

  // ---- 3 MLP layers; residual lives in At (bf16) ----
  #pragma unroll 1
  for (int l = 0; l < 3; ++l) {
    const u16* wp = (l == 0) ? w0 : (l == 1) ? w1 : w2;
    RUN_LAYER32(wp, 8);
    __syncthreads();                     // all At MFMA reads done

    if (l < 2) {
      const float* bp = (l == 0) ? b0 : b1;
      float bn = bp[ncol];
      #pragma unroll
      for (int rg = 0; rg < 16; ++rg) {
        int mm = wr32 + ROW_OF(rg);
        u16* p = (u16*)AT_ADDR(mm, ncol);
        float xn = bf2f(*p) + fmaxf(acc[rg] + bn, 0.f);
        *p = f2bfu(xn);                  // owner-thread RMW (disjoint)
        acc[rg] = 0.f;
      }
    } else {
      float bn = b2[ncol];
      #pragma unroll
      for (int rg = 0; rg < 16; ++rg) {
        int mm = wr32 + ROW_OF(rg);
        int row = r0 + mm;
        float nv = (row < NN) ? nodes[(size_t)row * 256 + ncol] : 0.f;
        acc[rg] = nv + bf2f(*(const u16*)AT_ADDR(mm, ncol)) + acc[rg] + bn;
      }
    }
  }

  // ---- final LayerNorm ----
  LN_STATS32();
  {
    float scl = lnOs[ncol], bia = lnOb[ncol];
    #pragma unroll
    for (int rg = 0; rg < 16; ++rg) {
      int mm = wr32 + ROW_OF(rg);
      int row = r0 + mm;
      if (row < NN)
        out[(size_t)row * 256 + ncol] =
            (acc[rg] - murs[mm][0]) * murs[mm][1] * scl + bia;
    }
  }
}

// ---------------------------------------------------------------------------
extern "C" void kernel_launch(void* const* d_in, const int* in_sizes, int n_in,
                              void* d_out, int out_size, void* d_ws, size_t ws_size,
                              hipStream_t stream)
{
  const float* nodes = (const float*)d_in[0];
  const float* edges = (const float*)d_in[1];
  const int* senders = (const int*)d_in[2];
  const int* receivers = (const int*)d_in[3];
  const float* Wmsg = (const float*)d_in[4];
  const float* W0 = (const float*)d_in[5];
  const float* b0 = (const float*)d_in[6];
  const float* W1 = (const float*)d_in[7];
  const float* b1 = (const float*)d_in[8];
  const float* W2 = (const float*)d_in[9];
  const float* b2 = (const float*)d_in[10];
  const float* lnAs = (const float*)d_in[11];
  const float* lnAb = (const float*)d_in[12];
  const float* lnOs = (const float*)d_in[13];
  const float* lnOb = (const float*)d_in[14];
  float* out = (float*)d_out;
  (void)in_sizes; (void)n_in; (void)out_size; (void)ws_size;

  char* w = (char*)d_ws;
  size_t off = 0;
  auto take = [&](size_t b) { void* p = w + off; off += (b + 511) & ~(size_t)511; return p; };

  u16*   nodes_bf = (u16*)take((size_t)NN * 256 * 2);
  u16*   wmsg_p   = (u16*)take(320 * 256 * 2);
  u16*   w0_p     = (u16*)take(256 * 256 * 2);
  u16*   w1_p     = (u16*)take(256 * 256 * 2);
  u16*   w2_p     = (u16*)take(256 * 256 * 2);
  u16*   X        = (u16*)take((size_t)NN * 320 * 2);
  int*   cnt      = (int*)take((size_t)NN * 4);
  int*   loc      = (int*)take((size_t)NN * 4);
  int*   offs     = (int*)take((size_t)(NN + 1) * 4);
  int*   cursor   = (int*)take((size_t)NN * 4);
  int2*  s_pair   = (int2*)take((size_t)NE * 8);
  int*   bsum     = (int*)take(256 * 4);
  int*   bpre     = (int*)take(256 * 4);

  const int NB = (NN + 255) / 256;  // 196

  hipMemsetAsync(cnt, 0, (size_t)NN * 4, stream);
  k_prep<<<NB_CVT + NB_PACK + NB_HIST, 256, 0, stream>>>(
      nodes, nodes_bf, Wmsg, W0, W1, W2, wmsg_p, w0_p, w1_p, w2_p,
      receivers, cnt);

  k_scan1<<<NB, 256, 0, stream>>>(cnt, loc, bsum);
  k_scan2<<<1, 256, 0, stream>>>(bsum, bpre, NB);
  k_scan3<<<NB, 256, 0, stream>>>(loc, bpre, offs, cursor);
  k_scatter<<<(NE + 255) / 256, 256, 0, stream>>>(senders, receivers, cursor, s_pair);

  k_aggr<<<NN / 4, 256, 0, stream>>>(nodes_bf, edges, offs, s_pair, X);

  const int MB = (NN + 63) / 64;    // 782
  k_fused<<<MB, 1024, 0, stream>>>(X, nodes, wmsg_p, w0_p, w1_p, w2_p,
                                   b0, b1, b2, lnAs, lnAb, lnOs, lnOb, out);
}

// Round 16
// 233.075 us; speedup vs baseline: 1.2685x; 1.2685x over previous
//
#include <hip/hip_runtime.h>

#define NN 50000
#define NE 400000

typedef unsigned short u16;
typedef unsigned int   u32;
typedef __bf16 bf16x4 __attribute__((ext_vector_type(4)));
typedef __bf16 bf16x8 __attribute__((ext_vector_type(8)));
typedef float  f32x4  __attribute__((ext_vector_type(4)));

union ABFrag { bf16x8 v; bf16x4 h[2]; };
union BFrag  { uint4 u; bf16x8 v; };

__device__ __forceinline__ u16 f2bfu(float f) {
  u32 u = __builtin_bit_cast(u32, f);
  return (u16)((u + 0x7FFFu + ((u >> 16) & 1u)) >> 16);  // RNE f32->bf16
}
__device__ __forceinline__ float bf2f(u16 u) {
  return __builtin_bit_cast(float, (u32)u << 16);
}

// ---------------- prep: cvt + weight-pack + hist in ONE launch ---------------
// pack[((t*256+n)*4+g)*8+j] = W[32t + 4g + (j%4) + 16*(j/4)][n]
__device__ __forceinline__ void pack_one(const float* __restrict__ W,
                                         u16* __restrict__ P, int idx) {
  int k = idx >> 8, n = idx & 255;
  int t = k >> 5, kp = k & 31;
  int g = (kp & 15) >> 2;
  int j = (kp & 3) | ((kp >> 4) << 2);
  P[(((t << 8) + n) << 5) + (g << 3) + j] = f2bfu(W[idx]);
}

#define NB_CVT  12500
#define NB_PACK 1088
#define NB_HIST 1563

__global__ __launch_bounds__(256) void k_prep(
    const float* __restrict__ nodes, u16* __restrict__ nodes_bf,
    const float* __restrict__ Wm, const float* __restrict__ W0,
    const float* __restrict__ W1, const float* __restrict__ W2,
    u16* __restrict__ Pm, u16* __restrict__ P0,
    u16* __restrict__ P1, u16* __restrict__ P2,
    const int* __restrict__ recv, int* __restrict__ cnt)
{
  int b = blockIdx.x, t = threadIdx.x;
  if (b < NB_CVT) {
    int i = b * 256 + t;
    float4 f = ((const float4*)nodes)[i];
    ushort4 o;
    o.x = f2bfu(f.x); o.y = f2bfu(f.y); o.z = f2bfu(f.z); o.w = f2bfu(f.w);
    ((ushort4*)nodes_bf)[i] = o;
  } else if (b < NB_CVT + NB_PACK) {
    int idx = (b - NB_CVT) * 256 + t;
    const int S0 = 320 * 256, S1 = S0 + 65536, S2 = S1 + 65536;
    if (idx < S0)      pack_one(Wm, Pm, idx);
    else if (idx < S1) pack_one(W0, P0, idx - S0);
    else if (idx < S2) pack_one(W1, P1, idx - S1);
    else               pack_one(W2, P2, idx - S2);
  } else {
    int i = (b - NB_CVT - NB_PACK) * 256 + t;
    if (i < NE) atomicAdd(&cnt[recv[i]], 1);
  }
}

// ---------------- counting-sort scan + scatter -------------------------------
__global__ __launch_bounds__(256) void k_scan1(const int* __restrict__ cnt,
                                               int* __restrict__ loc,
                                               int* __restrict__ bsum) {
  __shared__ int sm[256];
  int t = threadIdx.x, i = blockIdx.x * 256 + t;
  int v = (i < NN) ? cnt[i] : 0;
  sm[t] = v;
  __syncthreads();
  #pragma unroll
  for (int d = 1; d < 256; d <<= 1) {
    int x = sm[t];
    int y = (t >= d) ? sm[t - d] : 0;
    __syncthreads();
    sm[t] = x + y;
    __syncthreads();
  }
  if (i < NN) loc[i] = sm[t] - v;
  if (t == 255) bsum[blockIdx.x] = sm[255];
}

__global__ __launch_bounds__(256) void k_scan2(int* __restrict__ bsum,
                                               int* __restrict__ bpre, int nb) {
  __shared__ int sm[256];
  int t = threadIdx.x;
  int v = (t < nb) ? bsum[t] : 0;
  sm[t] = v;
  __syncthreads();
  #pragma unroll
  for (int d = 1; d < 256; d <<= 1) {
    int x = sm[t];
    int y = (t >= d) ? sm[t - d] : 0;
    __syncthreads();
    sm[t] = x + y;
    __syncthreads();
  }
  if (t < nb) bpre[t] = sm[t] - v;
}

__global__ __launch_bounds__(256) void k_scan3(const int* __restrict__ loc,
                                               const int* __restrict__ bpre,
                                               int* __restrict__ offs,
                                               int* __restrict__ cursor) {
  int i = blockIdx.x * 256 + threadIdx.x;
  if (i < NN) {
    int o = loc[i] + bpre[blockIdx.x];
    offs[i] = o;
    cursor[i] = o;
  }
  if (i == NN - 1) offs[NN] = NE;
}

__global__ __launch_bounds__(256) void k_scatter(
    const int* __restrict__ snd, const int* __restrict__ recv,
    int* __restrict__ cursor, int2* __restrict__ s_pair) {
  int e = blockIdx.x * 256 + threadIdx.x;
  if (e < NE) {
    int p = atomicAdd(&cursor[recv[e]], 1);
    int2 pr; pr.x = snd[e]; pr.y = e;
    s_pair[p] = pr;
  }
}

// ---------------- aggregation: half-wave paired volleys (R13, at floor) ------
__global__ __launch_bounds__(256) void k_aggr(
    const u16* __restrict__ nodes_bf, const float* __restrict__ edges,
    const int* __restrict__ offs, const int2* __restrict__ s_pair,
    u16* __restrict__ X)
{
  const int node = blockIdx.x * 4 + (threadIdx.x >> 6);
  const int lane = threadIdx.x & 63;
  const int h = lane >> 5, c = lane & 31;
  const int beg = offs[node], end = offs[node + 1];

  float a0 = 0.f, a1 = 0.f, a2 = 0.f, a3 = 0.f;
  float a4 = 0.f, a5 = 0.f, a6 = 0.f, a7 = 0.f;
  float ae0 = 0.f, ae1 = 0.f;

  for (int jb = beg; jb < end; jb += 8) {
    int j = jb + (lane & 7);
    if (j >= end) j = end - 1;
    int2 pr = s_pair[j];
    const int rem = end - jb;

#define PGATHER(K) \
    int s##K = __shfl(pr.x, 2 * K + h); \
    int e##K = __shfl(pr.y, 2 * K + h); \
    uint4 n##K = *(const uint4*)(nodes_bf + (size_t)s##K * 256 + (c << 3)); \
    float2 v##K = *(const float2*)(edges + (size_t)e##K * 64 + (c << 1));

    PGATHER(0) PGATHER(1) PGATHER(2) PGATHER(3)
#undef PGATHER

#define PACC(K) \
    if (rem > 2 * K + h) { \
      a0 += bf2f((u16)n##K.x); a1 += bf2f((u16)(n##K.x >> 16)); \
      a2 += bf2f((u16)n##K.y); a3 += bf2f((u16)(n##K.y >> 16)); \
      a4 += bf2f((u16)n##K.z); a5 += bf2f((u16)(n##K.z >> 16)); \
      a6 += bf2f((u16)n##K.w); a7 += bf2f((u16)(n##K.w >> 16)); \
      ae0 += v##K.x; ae1 += v##K.y; }

    PACC(0) PACC(1) PACC(2) PACC(3)
#undef PACC
  }

  a0 += __shfl_xor(a0, 32); a1 += __shfl_xor(a1, 32);
  a2 += __shfl_xor(a2, 32); a3 += __shfl_xor(a3, 32);
  a4 += __shfl_xor(a4, 32); a5 += __shfl_xor(a5, 32);
  a6 += __shfl_xor(a6, 32); a7 += __shfl_xor(a7, 32);
  ae0 += __shfl_xor(ae0, 32); ae1 += __shfl_xor(ae1, 32);

  if (lane < 32) {
    u16* xr = X + (size_t)node * 320;
    uint4 o;
    o.x = (u32)f2bfu(a0) | ((u32)f2bfu(a1) << 16);
    o.y = (u32)f2bfu(a2) | ((u32)f2bfu(a3) << 16);
    o.z = (u32)f2bfu(a4) | ((u32)f2bfu(a5) << 16);
    o.w = (u32)f2bfu(a6) | ((u32)f2bfu(a7) << 16);
    *(uint4*)(xr + (c << 3)) = o;
    *(u32*)(xr + 256 + (c << 1)) =
        (u32)f2bfu(ae0) | ((u32)f2bfu(ae1) << 16);
  }
}

// ---------------- fused dense chain: R13 skeleton, SQUARE 32x32 wave tile ----
// 1024 threads = 16 waves = 2 row-halves x 8 col-blocks of 32. Per lane per
// kk: 2 A-frags + 2 B-frags = 64B LDS (R13: 1+4 = 80B, -20%). Same At/Bt
// layouts, staging, and 16x16x32 MFMA as R13; acc[2][2] = 16 VGPRs.

#define AT_ADDR(r, c) (atb + ((((r) * 640) + ((c) * 2)) ^ (((r) & 7) << 4)))

#define WRBT(c, v) do { int _c = (c); \
  int _i = (((_c >> 10) << 13) + ((_c & 3) << 11) + (((_c & 1023) >> 2) << 3)) ^ ((_c & 3) << 4); \
  *(uint4*)&Bt[_i] = (v); } while (0)

#define MFMA_STEP(t) \
  _Pragma("unroll") \
  for (int kk = 0; kk < 2; ++kk) { \
    const int kc = (((t) * 2 + kk) << 5) + (g << 2); \
    ABFrag a0_, a1_; \
    a0_.h[0] = *(const bf16x4*)AT_ADDR(wrB + l16, kc); \
    a0_.h[1] = *(const bf16x4*)AT_ADDR(wrB + l16, kc + 16); \
    a1_.h[0] = *(const bf16x4*)AT_ADDR(wrB + 16 + l16, kc); \
    a1_.h[1] = *(const bf16x4*)AT_ADDR(wrB + 16 + l16, kc + 16); \
    BFrag b0_, b1_; \
    b0_.u = *(const uint4*)&Bt[((kk << 13) + (g << 11) + ((wcB + l16) << 3)) ^ (g << 4)]; \
    b1_.u = *(const uint4*)&Bt[((kk << 13) + (g << 11) + ((wcB + 16 + l16) << 3)) ^ (g << 4)]; \
    acc[0][0] = __builtin_amdgcn_mfma_f32_16x16x32_bf16(a0_.v, b0_.v, acc[0][0], 0, 0, 0); \
    acc[0][1] = __builtin_amdgcn_mfma_f32_16x16x32_bf16(a0_.v, b1_.v, acc[0][1], 0, 0, 0); \
    acc[1][0] = __builtin_amdgcn_mfma_f32_16x16x32_bf16(a1_.v, b0_.v, acc[1][0], 0, 0, 0); \
    acc[1][1] = __builtin_amdgcn_mfma_f32_16x16x32_bf16(a1_.v, b1_.v, acc[1][1], 0, 0, 0); \
  }

#define RUN_LAYER(wp, T) do { \
  const u16* pb = (wp) + ((size_t)tid << 3); \
  uint4 p0 = *(const uint4*)(pb); \
  uint4 p1 = *(const uint4*)(pb + 8192); \
  _Pragma("unroll 1") \
  for (int t = 0; t < (T); ++t) { \
    __syncthreads(); \
    WRBT(tid, p0); WRBT(tid + 1024, p1); \
    if (t + 1 < (T)) { \
      const u16* nb = pb + ((size_t)(t + 1) << 14); \
      p0 = *(const uint4*)nb; p1 = *(const uint4*)(nb + 8192); \
    } \
    __syncthreads(); \
    MFMA_STEP(t) \
  } \
} while (0)

// rows of acc[mf][*][r]: mm = wrB + mf*16 + g*4 + r; cols: n = wcB + qq*16 + l16
#define LN_STATS() do { \
  _Pragma("unroll") \
  for (int mf = 0; mf < 2; ++mf) { \
    _Pragma("unroll") \
    for (int r = 0; r < 4; ++r) { \
      float v0 = acc[mf][0][r], v1 = acc[mf][1][r]; \
      float s = v0 + v1, s2 = v0 * v0 + v1 * v1; \
      s  += __shfl_xor(s, 1);  s  += __shfl_xor(s, 2);  s  += __shfl_xor(s, 4);  s  += __shfl_xor(s, 8); \
      s2 += __shfl_xor(s2, 1); s2 += __shfl_xor(s2, 2); s2 += __shfl_xor(s2, 4); s2 += __shfl_xor(s2, 8); \
      if (l16 == 0) { int mm = wrB + (mf << 4) + g4 + r; red[mm][wcH] = s; red[mm][wcH + 1] = s2; } \
    } \
  } \
  __syncthreads(); \
  if (tid < 64) { \
    float s = 0.f, s2 = 0.f; \
    _Pragma("unroll") \
    for (int i = 0; i < 8; ++i) { s += red[tid][2 * i]; s2 += red[tid][2 * i + 1]; } \
    float mu  = s * (1.f / 256.f); \
    float var = s2 * (1.f / 256.f) - mu * mu; \
    murs[tid][0] = mu; murs[tid][1] = rsqrtf(var + 1e-6f); \
  } \
  __syncthreads(); \
} while (0)

__global__ __launch_bounds__(1024)
void k_fused(
    const u16* __restrict__ X, const float* __restrict__ nodes,
    const u16* __restrict__ wm, const u16* __restrict__ w0,
    const u16* __restrict__ w1, const u16* __restrict__ w2,
    const float* __restrict__ b0, const float* __restrict__ b1,
    const float* __restrict__ b2,
    const float* __restrict__ lnAs, const float* __restrict__ lnAb,
    const float* __restrict__ lnOs, const float* __restrict__ lnOb,
    float* __restrict__ out)
{
  __shared__ u16 At[64 * 320];     // XOR-swizzled: byte ^= (row&7)<<4
  __shared__ u16 Bt[16384];        // K=64 step: [kk][g][n][j] ^ (g<<4) u16-swz
  __shared__ float red[64][16];
  __shared__ float murs[64][2];

  const int tid = threadIdx.x;
  const int lane = tid & 63;
  const int w16 = tid >> 6;              // 0..15
  const int wrB = (w16 >> 3) << 5;       // row base: 0 or 32
  const int wcB = (w16 & 7) << 5;        // col base: 0,32,...,224
  const int wcH = (w16 & 7) << 1;
  const int l16 = lane & 15, g = lane >> 4, g4 = g << 2;
  const int r0 = blockIdx.x * 64;

  char* const atb = (char*)At;

  // ---- stage X (bf16, K=320) into swizzled At ----
  #pragma unroll
  for (int it = 0; it < 3; ++it) {
    int c = tid + it * 1024;
    if (c < 2560) {
      int r = c / 40, seg = c - r * 40;
      int row = r0 + r;
      uint4 v = {0u, 0u, 0u, 0u};
      if (row < NN) v = *(const uint4*)(X + (size_t)row * 320 + seg * 8);
      *(uint4*)(atb + ((r * 640 + seg * 16) ^ ((r & 7) << 4))) = v;
    }
  }

  f32x4 acc[2][2];
  const f32x4 z = {0.f, 0.f, 0.f, 0.f};
  #pragma unroll
  for (int i = 0; i < 2; ++i)
    #pragma unroll
    for (int q = 0; q < 2; ++q) acc[i][q] = z;

  // ---- GEMM: X @ Wmsg (K=320, 5 steps of 64) ----
  RUN_LAYER(wm, 5);

  // ---- aggr epilogue: v = relu(acc) + nodes ----
  #pragma unroll
  for (int mf = 0; mf < 2; ++mf)
    #pragma unroll
    for (int q = 0; q < 2; ++q) {
      int n = wcB + (q << 4) + l16;
      #pragma unroll
      for (int r = 0; r < 4; ++r) {
        int row = r0 + wrB + (mf << 4) + g4 + r;
        float nv = (row < NN) ? nodes[(size_t)row * 256 + n] : 0.f;
        acc[mf][q][r] = fmaxf(acc[mf][q][r], 0.f) + nv;
      }
    }
  LN_STATS();                            // barrier inside also fences At reads
  // h = LN_a(v) -> bf16 into At (residual + next A operand)
  #pragma unroll
  for (int mf = 0; mf < 2; ++mf)
    #pragma unroll
    for (int q = 0; q < 2; ++q) {
      int n = wcB + (q << 4) + l16;
      float scl = lnAs[n], bia = lnAb[n];
      #pragma unroll
      for (int r = 0; r < 4; ++r) {
        int mm = wrB + (mf << 4) + g4 + r;
        float h = (acc[mf][q][r] - murs[mm][0]) * murs[mm][1] * scl + bia;
        *(u16*)AT_ADDR(mm, n) = f2bfu(h);
        acc[mf][q][r] = 0.f;
      }
    }

  // ---- 3 MLP layers; residual lives in At (bf16) ----
  #pragma unroll 1
  for (int l = 0; l < 3; ++l) {
    const u16* wp = (l == 0) ? w0 : (l == 1) ? w1 : w2;
    RUN_LAYER(wp, 4);
    __syncthreads();                     // all At MFMA reads done

    if (l < 2) {
      const float* bp = (l == 0) ? b0 : b1;
      #pragma unroll
      for (int mf = 0; mf < 2; ++mf)
        #pragma unroll
        for (int q = 0; q < 2; ++q) {
          int n = wcB + (q << 4) + l16;
          float bn = bp[n];
          #pragma unroll
          for (int r = 0; r < 4; ++r) {
            int mm = wrB + (mf << 4) + g4 + r;
            u16* p = (u16*)AT_ADDR(mm, n);
            float xn = bf2f(*p) + fmaxf(acc[mf][q][r] + bn, 0.f);
            *p = f2bfu(xn);              // owner-thread RMW (disjoint)
            acc[mf][q][r] = 0.f;
          }
        }
    } else {
      #pragma unroll
      for (int mf = 0; mf < 2; ++mf)
        #pragma unroll
        for (int q = 0; q < 2; ++q) {
          int n = wcB + (q << 4) + l16;
          float bn = b2[n];
          #pragma unroll
          for (int r = 0; r < 4; ++r) {
            int mm = wrB + (mf << 4) + g4 + r;
            int row = r0 + mm;
            float nv = (row < NN) ? nodes[(size_t)row * 256 + n] : 0.f;
            acc[mf][q][r] = nv + bf2f(*(const u16*)AT_ADDR(mm, n)) + acc[mf][q][r] + bn;
          }
        }
    }
  }

  // ---- final LayerNorm ----
  LN_STATS();
  #pragma unroll
  for (int mf = 0; mf < 2; ++mf)
    #pragma unroll
    for (int q = 0; q < 2; ++q) {
      int n = wcB + (q << 4) + l16;
      float scl = lnOs[n], bia = lnOb[n];
      #pragma unroll
      for (int r = 0; r < 4; ++r) {
        int mm = wrB + (mf << 4) + g4 + r;
        int row = r0 + mm;
        if (row < NN)
          out[(size_t)row * 256 + n] =
              (acc[mf][q][r] - murs[mm][0]) * murs[mm][1] * scl + bia;
      }
    }
}

// ---------------------------------------------------------------------------
extern "C" void kernel_launch(void* const* d_in, const int* in_sizes, int n_in,
                              void* d_out, int out_size, void* d_ws, size_t ws_size,
                              hipStream_t stream)
{
  const float* nodes = (const float*)d_in[0];
  const float* edges = (const float*)d_in[1];
  const int* senders = (const int*)d_in[2];
  const int* receivers = (const int*)d_in[3];
  const float* Wmsg = (const float*)d_in[4];
  const float* W0 = (const float*)d_in[5];
  const float* b0 = (const float*)d_in[6];
  const float* W1 = (const float*)d_in[7];
  const float* b1 = (const float*)d_in[8];
  const float* W2 = (const float*)d_in[9];
  const float* b2 = (const float*)d_in[10];
  const float* lnAs = (const float*)d_in[11];
  const float* lnAb = (const float*)d_in[12];
  const float* lnOs = (const float*)d_in[13];
  const float* lnOb = (const float*)d_in[14];
  float* out = (float*)d_out;
  (void)in_sizes; (void)n_in; (void)out_size; (void)ws_size;

  char* w = (char*)d_ws;
  size_t off = 0;
  auto take = [&](size_t b) { void* p = w + off; off += (b + 511) & ~(size_t)511; return p; };

  u16*   nodes_bf = (u16*)take((size_t)NN * 256 * 2);
  u16*   wmsg_p   = (u16*)take(320 * 256 * 2);
  u16*   w0_p     = (u16*)take(256 * 256 * 2);
  u16*   w1_p     = (u16*)take(256 * 256 * 2);
  u16*   w2_p     = (u16*)take(256 * 256 * 2);
  u16*   X        = (u16*)take((size_t)NN * 320 * 2);
  int*   cnt      = (int*)take((size_t)NN * 4);
  int*   loc      = (int*)take((size_t)NN * 4);
  int*   offs     = (int*)take((size_t)(NN + 1) * 4);
  int*   cursor   = (int*)take((size_t)NN * 4);
  int2*  s_pair   = (int2*)take((size_t)NE * 8);
  int*   bsum     = (int*)take(256 * 4);
  int*   bpre     = (int*)take(256 * 4);

  const int NB = (NN + 255) / 256;  // 196

  hipMemsetAsync(cnt, 0, (size_t)NN * 4, stream);
  k_prep<<<NB_CVT + NB_PACK + NB_HIST, 256, 0, stream>>>(
      nodes, nodes_bf, Wmsg, W0, W1, W2, wmsg_p, w0_p, w1_p, w2_p,
      receivers, cnt);

  k_scan1<<<NB, 256, 0, stream>>>(cnt, loc, bsum);
  k_scan2<<<1, 256, 0, stream>>>(bsum, bpre, NB);
  k_scan3<<<NB, 256, 0, stream>>>(loc, bpre, offs, cursor);
  k_scatter<<<(NE + 255) / 256, 256, 0, stream>>>(senders, receivers, cursor, s_pair);

  k_aggr<<<NN / 4, 256, 0, stream>>>(nodes_bf, edges, offs, s_pair, X);

  const int MB = (NN + 63) / 64;    // 782
  k_fused<<<MB, 1024, 0, stream>>>(X, nodes, wmsg_p, w0_p, w1_p, w2_p,
                                   b0, b1, b2, lnAs, lnAb, lnOs, lnOb, out);
}

// Round 17
// 218.944 us; speedup vs baseline: 1.3504x; 1.0645x over previous
//
#include <hip/hip_runtime.h>

#define NN 50000
#define NE 400000

typedef unsigned short u16;
typedef unsigned int   u32;
typedef __bf16 bf16x4 __attribute__((ext_vector_type(4)));
typedef __bf16 bf16x8 __attribute__((ext_vector_type(8)));
typedef float  f32x4  __attribute__((ext_vector_type(4)));

union ABFrag { bf16x8 v; bf16x4 h[2]; };
union BFrag  { uint4 u; bf16x8 v; };

__device__ __forceinline__ u16 f2bfu(float f) {
  u32 u = __builtin_bit_cast(u32, f);
  return (u16)((u + 0x7FFFu + ((u >> 16) & 1u)) >> 16);  // RNE f32->bf16
}
__device__ __forceinline__ float bf2f(u16 u) {
  return __builtin_bit_cast(float, (u32)u << 16);
}

// ---------------- prep: cvt + weight-pack + hist in ONE launch ---------------
__device__ __forceinline__ void pack_one(const float* __restrict__ W,
                                         u16* __restrict__ P, int idx) {
  int k = idx >> 8, n = idx & 255;
  int t = k >> 5, kp = k & 31;
  int g = (kp & 15) >> 2;
  int j = (kp & 3) | ((kp >> 4) << 2);
  P[(((t << 8) + n) << 5) + (g << 3) + j] = f2bfu(W[idx]);
}

#define NB_CVT  12500
#define NB_PACK 1088
#define NB_HIST 1563

__global__ __launch_bounds__(256) void k_prep(
    const float* __restrict__ nodes, u16* __restrict__ nodes_bf,
    const float* __restrict__ Wm, const float* __restrict__ W0,
    const float* __restrict__ W1, const float* __restrict__ W2,
    u16* __restrict__ Pm, u16* __restrict__ P0,
    u16* __restrict__ P1, u16* __restrict__ P2,
    const int* __restrict__ recv, int* __restrict__ cnt)
{
  int b = blockIdx.x, t = threadIdx.x;
  if (b < NB_CVT) {
    int i = b * 256 + t;
    float4 f = ((const float4*)nodes)[i];
    ushort4 o;
    o.x = f2bfu(f.x); o.y = f2bfu(f.y); o.z = f2bfu(f.z); o.w = f2bfu(f.w);
    ((ushort4*)nodes_bf)[i] = o;
  } else if (b < NB_CVT + NB_PACK) {
    int idx = (b - NB_CVT) * 256 + t;
    const int S0 = 320 * 256, S1 = S0 + 65536, S2 = S1 + 65536;
    if (idx < S0)      pack_one(Wm, Pm, idx);
    else if (idx < S1) pack_one(W0, P0, idx - S0);
    else if (idx < S2) pack_one(W1, P1, idx - S1);
    else               pack_one(W2, P2, idx - S2);
  } else {
    int i = (b - NB_CVT - NB_PACK) * 256 + t;
    if (i < NE) atomicAdd(&cnt[recv[i]], 1);
  }
}

// ---------------- counting-sort scan + scatter -------------------------------
__global__ __launch_bounds__(256) void k_scan1(const int* __restrict__ cnt,
                                               int* __restrict__ loc,
                                               int* __restrict__ bsum) {
  __shared__ int sm[256];
  int t = threadIdx.x, i = blockIdx.x * 256 + t;
  int v = (i < NN) ? cnt[i] : 0;
  sm[t] = v;
  __syncthreads();
  #pragma unroll
  for (int d = 1; d < 256; d <<= 1) {
    int x = sm[t];
    int y = (t >= d) ? sm[t - d] : 0;
    __syncthreads();
    sm[t] = x + y;
    __syncthreads();
  }
  if (i < NN) loc[i] = sm[t] - v;
  if (t == 255) bsum[blockIdx.x] = sm[255];
}

__global__ __launch_bounds__(256) void k_scan2(int* __restrict__ bsum,
                                               int* __restrict__ bpre, int nb) {
  __shared__ int sm[256];
  int t = threadIdx.x;
  int v = (t < nb) ? bsum[t] : 0;
  sm[t] = v;
  __syncthreads();
  #pragma unroll
  for (int d = 1; d < 256; d <<= 1) {
    int x = sm[t];
    int y = (t >= d) ? sm[t - d] : 0;
    __syncthreads();
    sm[t] = x + y;
    __syncthreads();
  }
  if (t < nb) bpre[t] = sm[t] - v;
}

__global__ __launch_bounds__(256) void k_scan3(const int* __restrict__ loc,
                                               const int* __restrict__ bpre,
                                               int* __restrict__ offs,
                                               int* __restrict__ cursor) {
  int i = blockIdx.x * 256 + threadIdx.x;
  if (i < NN) {
    int o = loc[i] + bpre[blockIdx.x];
    offs[i] = o;
    cursor[i] = o;
  }
  if (i == NN - 1) offs[NN] = NE;
}

__global__ __launch_bounds__(256) void k_scatter(
    const int* __restrict__ snd, const int* __restrict__ recv,
    int* __restrict__ cursor, int2* __restrict__ s_pair) {
  int e = blockIdx.x * 256 + threadIdx.x;
  if (e < NE) {
    int p = atomicAdd(&cursor[recv[e]], 1);
    int2 pr; pr.x = snd[e]; pr.y = e;
    s_pair[p] = pr;
  }
}

// ---------------- aggregation: half-wave paired volleys (at latency floor) ---
__global__ __launch_bounds__(256) void k_aggr(
    const u16* __restrict__ nodes_bf, const float* __restrict__ edges,
    const int* __restrict__ offs, const int2* __restrict__ s_pair,
    u16* __restrict__ X)
{
  const int node = blockIdx.x * 4 + (threadIdx.x >> 6);
  const int lane = threadIdx.x & 63;
  const int h = lane >> 5, c = lane & 31;
  const int beg = offs[node], end = offs[node + 1];

  float a0 = 0.f, a1 = 0.f, a2 = 0.f, a3 = 0.f;
  float a4 = 0.f, a5 = 0.f, a6 = 0.f, a7 = 0.f;
  float ae0 = 0.f, ae1 = 0.f;

  for (int jb = beg; jb < end; jb += 8) {
    int j = jb + (lane & 7);
    if (j >= end) j = end - 1;
    int2 pr = s_pair[j];
    const int rem = end - jb;

#define PGATHER(K) \
    int s##K = __shfl(pr.x, 2 * K + h); \
    int e##K = __shfl(pr.y, 2 * K + h); \
    uint4 n##K = *(const uint4*)(nodes_bf + (size_t)s##K * 256 + (c << 3)); \
    float2 v##K = *(const float2*)(edges + (size_t)e##K * 64 + (c << 1));

    PGATHER(0) PGATHER(1) PGATHER(2) PGATHER(3)
#undef PGATHER

#define PACC(K) \
    if (rem > 2 * K + h) { \
      a0 += bf2f((u16)n##K.x); a1 += bf2f((u16)(n##K.x >> 16)); \
      a2 += bf2f((u16)n##K.y); a3 += bf2f((u16)(n##K.y >> 16)); \
      a4 += bf2f((u16)n##K.z); a5 += bf2f((u16)(n##K.z >> 16)); \
      a6 += bf2f((u16)n##K.w); a7 += bf2f((u16)(n##K.w >> 16)); \
      ae0 += v##K.x; ae1 += v##K.y; }

    PACC(0) PACC(1) PACC(2) PACC(3)
#undef PACC
  }

  a0 += __shfl_xor(a0, 32); a1 += __shfl_xor(a1, 32);
  a2 += __shfl_xor(a2, 32); a3 += __shfl_xor(a3, 32);
  a4 += __shfl_xor(a4, 32); a5 += __shfl_xor(a5, 32);
  a6 += __shfl_xor(a6, 32); a7 += __shfl_xor(a7, 32);
  ae0 += __shfl_xor(ae0, 32); ae1 += __shfl_xor(ae1, 32);

  if (lane < 32) {
    u16* xr = X + (size_t)node * 320;
    uint4 o;
    o.x = (u32)f2bfu(a0) | ((u32)f2bfu(a1) << 16);
    o.y = (u32)f2bfu(a2) | ((u32)f2bfu(a3) << 16);
    o.z = (u32)f2bfu(a4) | ((u32)f2bfu(a5) << 16);
    o.w = (u32)f2bfu(a6) | ((u32)f2bfu(a7) << 16);
    *(uint4*)(xr + (c << 3)) = o;
    *(u32*)(xr + 256 + (c << 1)) =
        (u32)f2bfu(ae0) | ((u32)f2bfu(ae1) << 16);
  }
}

// ---------------- fully fused dense chain (R8/R13 variant — measured best) ---
#define AT_ADDR(r, c) (atb + ((((r) * 640) + ((c) * 2)) ^ (((r) & 7) << 4)))

#define WRBT(c, v) do { int _c = (c); \
  int _i = (((_c >> 10) << 13) + ((_c & 3) << 11) + (((_c & 1023) >> 2) << 3)) ^ ((_c & 3) << 4); \
  *(uint4*)&Bt[_i] = (v); } while (0)

#define MFMA_STEP(t) \
  _Pragma("unroll") \
  for (int kk = 0; kk < 2; ++kk) { \
    ABFrag a; \
    const int kc = (((t) * 2 + kk) << 5) + (g << 2); \
    const int m = wr16 + l16; \
    a.h[0] = *(const bf16x4*)AT_ADDR(m, kc); \
    a.h[1] = *(const bf16x4*)AT_ADDR(m, kc + 16); \
    _Pragma("unroll") \
    for (int q = 0; q < 4; ++q) { \
      BFrag b; \
      b.u = *(const uint4*)&Bt[((kk << 13) + (g << 11) + ((wcn + (q << 4) + l16) << 3)) ^ (g << 4)]; \
      acc[q] = __builtin_amdgcn_mfma_f32_16x16x32_bf16(a.v, b.v, acc[q], 0, 0, 0); \
    } \
  }

#define RUN_LAYER(wp, T) do { \
  const u16* pb = (wp) + ((size_t)tid << 3); \
  uint4 p0 = *(const uint4*)(pb); \
  uint4 p1 = *(const uint4*)(pb + 8192); \
  _Pragma("unroll 1") \
  for (int t = 0; t < (T); ++t) { \
    __syncthreads(); \
    WRBT(tid, p0); WRBT(tid + 1024, p1); \
    if (t + 1 < (T)) { \
      const u16* nb = pb + ((size_t)(t + 1) << 14); \
      p0 = *(const uint4*)nb; p1 = *(const uint4*)(nb + 8192); \
    } \
    __syncthreads(); \
    MFMA_STEP(t) \
  } \
} while (0)

#define LN_STATS() do { \
  _Pragma("unroll") \
  for (int r = 0; r < 4; ++r) { \
    float s  = acc[0][r] + acc[1][r] + acc[2][r] + acc[3][r]; \
    float s2 = acc[0][r]*acc[0][r] + acc[1][r]*acc[1][r] + acc[2][r]*acc[2][r] + acc[3][r]*acc[3][r]; \
    s  += __shfl_xor(s, 1);  s  += __shfl_xor(s, 2);  s  += __shfl_xor(s, 4);  s  += __shfl_xor(s, 8); \
    s2 += __shfl_xor(s2, 1); s2 += __shfl_xor(s2, 2); s2 += __shfl_xor(s2, 4); s2 += __shfl_xor(s2, 8); \
    if (l16 == 0) { int m = wr16 + g4 + r; red[m][wc2] = s; red[m][wc2 + 1] = s2; } \
  } \
  __syncthreads(); \
  if (tid < 64) { \
    float s  = red[tid][0] + red[tid][2] + red[tid][4] + red[tid][6]; \
    float s2 = red[tid][1] + red[tid][3] + red[tid][5] + red[tid][7]; \
    float mu  = s * (1.f / 256.f); \
    float var = s2 * (1.f / 256.f) - mu * mu; \
    murs[tid][0] = mu; murs[tid][1] = rsqrtf(var + 1e-6f); \
  } \
  __syncthreads(); \
} while (0)

__global__ __launch_bounds__(1024)
void k_fused(
    const u16* __restrict__ X, const float* __restrict__ nodes,
    const u16* __restrict__ wm, const u16* __restrict__ w0,
    const u16* __restrict__ w1, const u16* __restrict__ w2,
    const float* __restrict__ b0, const float* __restrict__ b1,
    const float* __restrict__ b2,
    const float* __restrict__ lnAs, const float* __restrict__ lnAb,
    const float* __restrict__ lnOs, const float* __restrict__ lnOb,
    float* __restrict__ out)
{
  __shared__ u16 At[64 * 320];     // XOR-swizzled: byte ^= (row&7)<<4
  __shared__ u16 Bt[16384];        // K=64 step: [kk][g][n][j] ^ (g<<4) u16-swz
  __shared__ float red[64][8];
  __shared__ float murs[64][2];

  const int tid = threadIdx.x;
  const int lane = tid & 63;
  const int w16 = tid >> 6;
  const int wr16 = (w16 >> 2) << 4;
  const int wcn = (w16 & 3) << 6;
  const int wc2 = (w16 & 3) << 1;
  const int l16 = lane & 15, g = lane >> 4, g4 = g << 2;
  const int r0 = blockIdx.x * 64;

  char* const atb = (char*)At;

  // ---- stage X (bf16, K=320) into swizzled At ----
  #pragma unroll
  for (int it = 0; it < 3; ++it) {
    int c = tid + it * 1024;
    if (c < 2560) {
      int r = c / 40, seg = c - r * 40;
      int row = r0 + r;
      uint4 v = {0u, 0u, 0u, 0u};
      if (row < NN) v = *(const uint4*)(X + (size_t)row * 320 + seg * 8);
      *(uint4*)(atb + ((r * 640 + seg * 16) ^ ((r & 7) << 4))) = v;
    }
  }

  f32x4 acc[4];
  const f32x4 z = {0.f, 0.f, 0.f, 0.f};
  #pragma unroll
  for (int q = 0; q < 4; ++q) acc[q] = z;

  // ---- GEMM: X @ Wmsg (K=320, 5 steps of 64) ----
  RUN_LAYER(wm, 5);

  // ---- aggr epilogue: v = relu(acc) + nodes ----
  #pragma unroll
  for (int q = 0; q < 4; ++q) {
    int n = wcn + (q << 4) + l16;
    #pragma unroll
    for (int r = 0; r < 4; ++r) {
      int row = r0 + wr16 + g4 + r;
      float nv = (row < NN) ? nodes[(size_t)row * 256 + n] : 0.f;
      acc[q][r] = fmaxf(acc[q][r], 0.f) + nv;
    }
  }
  LN_STATS();
  #pragma unroll
  for (int q = 0; q < 4; ++q) {
    int n = wcn + (q << 4) + l16;
    float scl = lnAs[n], bia = lnAb[n];
    #pragma unroll
    for (int r = 0; r < 4; ++r) {
      int m = wr16 + g4 + r;
      float h = (acc[q][r] - murs[m][0]) * murs[m][1] * scl + bia;
      *(u16*)AT_ADDR(m, n) = f2bfu(h);
      acc[q][r] = 0.f;
    }
  }

  // ---- 3 MLP layers; residual lives in At (bf16) ----
  #pragma unroll 1
  for (int l = 0; l < 3; ++l) {
    const u16* wp = (l == 0) ? w0 : (l == 1) ? w1 : w2;
    RUN_LAYER(wp, 4);
    __syncthreads();

    if (l < 2) {
      const float* bp = (l == 0) ? b0 : b1;
      #pragma unroll
      for (int q = 0; q < 4; ++q) {
        int n = wcn + (q << 4) + l16;
        float bn = bp[n];
        #pragma unroll
        for (int r = 0; r < 4; ++r) {
          int m = wr16 + g4 + r;
          u16* p = (u16*)AT_ADDR(m, n);
          float xn = bf2f(*p) + fmaxf(acc[q][r] + bn, 0.f);
          *p = f2bfu(xn);
          acc[q][r] = 0.f;
        }
      }
    } else {
      #pragma unroll
      for (int q = 0; q < 4; ++q) {
        int n = wcn + (q << 4) + l16;
        float bn = b2[n];
        #pragma unroll
        for (int r = 0; r < 4; ++r) {
          int m = wr16 + g4 + r;
          int row = r0 + m;
          float nv = (row < NN) ? nodes[(size_t)row * 256 + n] : 0.f;
          acc[q][r] = nv + bf2f(*(const u16*)AT_ADDR(m, n)) + acc[q][r] + bn;
        }
      }
    }
  }

  // ---- final LayerNorm ----
  LN_STATS();
  #pragma unroll
  for (int q = 0; q < 4; ++q) {
    int n = wcn + (q << 4) + l16;
    float scl = lnOs[n], bia = lnOb[n];
    #pragma unroll
    for (int r = 0; r < 4; ++r) {
      int m = wr16 + g4 + r;
      int row = r0 + m;
      if (row < NN)
        out[(size_t)row * 256 + n] =
            (acc[q][r] - murs[m][0]) * murs[m][1] * scl + bia;
    }
  }
}

// ---------------------------------------------------------------------------
extern "C" void kernel_launch(void* const* d_in, const int* in_sizes, int n_in,
                              void* d_out, int out_size, void* d_ws, size_t ws_size,
                              hipStream_t stream)
{
  const float* nodes = (const float*)d_in[0];
  const float* edges = (const float*)d_in[1];
  const int* senders = (const int*)d_in[2];
  const int* receivers = (const int*)d_in[3];
  const float* Wmsg = (const float*)d_in[4];
  const float* W0 = (const float*)d_in[5];
  const float* b0 = (const float*)d_in[6];
  const float* W1 = (const float*)d_in[7];
  const float* b1 = (const float*)d_in[8];
  const float* W2 = (const float*)d_in[9];
  const float* b2 = (const float*)d_in[10];
  const float* lnAs = (const float*)d_in[11];
  const float* lnAb = (const float*)d_in[12];
  const float* lnOs = (const float*)d_in[13];
  const float* lnOb = (const float*)d_in[14];
  float* out = (float*)d_out;
  (void)in_sizes; (void)n_in; (void)out_size; (void)ws_size;

  char* w = (char*)d_ws;
  size_t off = 0;
  auto take = [&](size_t b) { void* p = w + off; off += (b + 511) & ~(size_t)511; return p; };

  u16*   nodes_bf = (u16*)take((size_t)NN * 256 * 2);
  u16*   wmsg_p   = (u16*)take(320 * 256 * 2);
  u16*   w0_p     = (u16*)take(256 * 256 * 2);
  u16*   w1_p     = (u16*)take(256 * 256 * 2);
  u16*   w2_p     = (u16*)take(256 * 256 * 2);
  u16*   X        = (u16*)take((size_t)NN * 320 * 2);
  int*   cnt      = (int*)take((size_t)NN * 4);
  int*   loc      = (int*)take((size_t)NN * 4);
  int*   offs     = (int*)take((size_t)(NN + 1) * 4);
  int*   cursor   = (int*)take((size_t)NN * 4);
  int2*  s_pair   = (int2*)take((size_t)NE * 8);
  int*   bsum     = (int*)take(256 * 4);
  int*   bpre     = (int*)take(256 * 4);

  const int NB = (NN + 255) / 256;  // 196

  hipMemsetAsync(cnt, 0, (size_t)NN * 4, stream);
  k_prep<<<NB_CVT + NB_PACK + NB_HIST, 256, 0, stream>>>(
      nodes, nodes_bf, Wmsg, W0, W1, W2, wmsg_p, w0_p, w1_p, w2_p,
      receivers, cnt);

  k_scan1<<<NB, 256, 0, stream>>>(cnt, loc, bsum);
  k_scan2<<<1, 256, 0, stream>>>(bsum, bpre, NB);
  k_scan3<<<NB, 256, 0, stream>>>(loc, bpre, offs, cursor);
  k_scatter<<<(NE + 255) / 256, 256, 0, stream>>>(senders, receivers, cursor, s_pair);

  k_aggr<<<NN / 4, 256, 0, stream>>>(nodes_bf, edges, offs, s_pair, X);

  const int MB = (NN + 63) / 64;    // 782
  k_fused<<<MB, 1024, 0, stream>>>(X, nodes, wmsg_p, w0_p, w1_p, w2_p,
                                   b0, b1, b2, lnAs, lnAb, lnOs, lnOb, out);
}